// Round 1
// baseline (477.197 us; speedup 1.0000x reference)
//
#include <hip/hip_runtime.h>

#define NSER 65536
#define NT   1024
#define SEAS 24
#define SLEN (NT + SEAS)   // 1048 seasonal output columns

__device__ __forceinline__ float frcp(float x) { return __builtin_amdgcn_rcpf(x); }

__global__ __launch_bounds__(256) void es_kernel(
    const float* __restrict__ y,
    const int*   __restrict__ idxs,
    const float* __restrict__ lev_sms,
    const float* __restrict__ seas_sms,
    const float* __restrict__ init_seas,
    float* __restrict__ levels,
    float* __restrict__ seasout)
{
    const int i  = blockIdx.x * 256 + threadIdx.x;
    const int id = idxs[i];

    const float a  = 1.0f / (1.0f + __expf(-lev_sms[id]));
    const float b  = 1.0f / (1.0f + __expf(-seas_sms[id]));
    const float ia = 1.0f - a, ib = 1.0f - b;

    // season ring, kept in registers via static indexing (24-aligned unrolled blocks)
    float ring[SEAS];
    {
        const float* isrow = init_seas + (size_t)id * SEAS;
        #pragma unroll
        for (int k = 0; k < SEAS; ++k) ring[k] = __expf(isrow[k]);
    }

    const float* yr = y + (size_t)i * NT;
    float* lr = levels  + (size_t)i * NT;
    float* sr = seasout + (size_t)i * SLEN;

    // ---- head: y[0..23] ----
    float yb[SEAS];
    #pragma unroll
    for (int k = 0; k < SEAS/4; ++k) {
        float4 v = ((const float4*)yr)[k];
        yb[4*k]=v.x; yb[4*k+1]=v.y; yb[4*k+2]=v.z; yb[4*k+3]=v.w;
    }

    float lev = yb[0] * frcp(ring[0]);

    // outputs for t=0..23 (levels) and seasonal cols 0..47
    float lv[SEAS];
    float sh[2*SEAS];
    lv[0] = lev;
    #pragma unroll
    for (int k = 0; k < SEAS; ++k) sh[k] = ring[k];
    sh[SEAS] = ring[0];

    // steps t = 1..23, ring slot h = t
    #pragma unroll
    for (int j = 1; j < SEAS; ++j) {
        float s = ring[j], yt = yb[j];
        float nl = fmaf(a, yt * frcp(s), ia * lev);
        float ns = fmaf(b, yt * frcp(nl), ib * s);
        ring[j] = ns; lev = nl;
        lv[j] = nl; sh[SEAS + j] = ns;
    }
    #pragma unroll
    for (int k = 0; k < SEAS/4; ++k)
        ((float4*)lr)[k] = make_float4(lv[4*k],lv[4*k+1],lv[4*k+2],lv[4*k+3]);
    #pragma unroll
    for (int k = 0; k < (2*SEAS)/4; ++k)
        ((float4*)sr)[k] = make_float4(sh[4*k],sh[4*k+1],sh[4*k+2],sh[4*k+3]);

    // ---- main blocks: tb = 24, 48, ..., 984 (ring slot h = j since tb % 24 == 0) ----
    for (int tb = SEAS; tb < NT - 16; tb += SEAS) {
        float yv[SEAS], lvb[SEAS], nsb[SEAS];
        #pragma unroll
        for (int k = 0; k < SEAS/4; ++k) {
            float4 v = *(const float4*)(yr + tb + 4*k);
            yv[4*k]=v.x; yv[4*k+1]=v.y; yv[4*k+2]=v.z; yv[4*k+3]=v.w;
        }
        #pragma unroll
        for (int j = 0; j < SEAS; ++j) {
            float s = ring[j], yt = yv[j];
            float nl = fmaf(a, yt * frcp(s), ia * lev);
            float ns = fmaf(b, yt * frcp(nl), ib * s);
            ring[j] = ns; lev = nl;
            lvb[j] = nl; nsb[j] = ns;
        }
        #pragma unroll
        for (int k = 0; k < SEAS/4; ++k)
            *(float4*)(lr + tb + 4*k) = make_float4(lvb[4*k],lvb[4*k+1],lvb[4*k+2],lvb[4*k+3]);
        #pragma unroll
        for (int k = 0; k < SEAS/4; ++k)
            *(float4*)(sr + SEAS + tb + 4*k) = make_float4(nsb[4*k],nsb[4*k+1],nsb[4*k+2],nsb[4*k+3]);
    }

    // ---- tail: tb = 1008, 16 steps (1008 % 24 == 0, ring slot h = j) ----
    {
        const int tb = NT - 16;
        float yv[16], lvb[16], nsb[16];
        #pragma unroll
        for (int k = 0; k < 4; ++k) {
            float4 v = *(const float4*)(yr + tb + 4*k);
            yv[4*k]=v.x; yv[4*k+1]=v.y; yv[4*k+2]=v.z; yv[4*k+3]=v.w;
        }
        #pragma unroll
        for (int j = 0; j < 16; ++j) {
            float s = ring[j], yt = yv[j];
            float nl = fmaf(a, yt * frcp(s), ia * lev);
            float ns = fmaf(b, yt * frcp(nl), ib * s);
            ring[j] = ns; lev = nl;
            lvb[j] = nl; nsb[j] = ns;
        }
        #pragma unroll
        for (int k = 0; k < 4; ++k)
            *(float4*)(lr + tb + 4*k) = make_float4(lvb[4*k],lvb[4*k+1],lvb[4*k+2],lvb[4*k+3]);
        #pragma unroll
        for (int k = 0; k < 4; ++k)
            *(float4*)(sr + SEAS + tb + 4*k) = make_float4(nsb[4*k],nsb[4*k+1],nsb[4*k+2],nsb[4*k+3]);
    }
}

extern "C" void kernel_launch(void* const* d_in, const int* in_sizes, int n_in,
                              void* d_out, int out_size, void* d_ws, size_t ws_size,
                              hipStream_t stream) {
    const float* y         = (const float*)d_in[0];
    const int*   idxs      = (const int*)d_in[1];
    const float* lev_sms   = (const float*)d_in[2];
    const float* seas_sms  = (const float*)d_in[3];
    const float* init_seas = (const float*)d_in[4];

    float* levels  = (float*)d_out;
    float* seasout = levels + (size_t)NSER * NT;

    es_kernel<<<NSER/256, 256, 0, stream>>>(y, idxs, lev_sms, seas_sms, init_seas,
                                            levels, seasout);
}

// Round 2
// 353.533 us; speedup vs baseline: 1.3498x; 1.3498x over previous
//
#include <hip/hip_runtime.h>

#define NSER 65536
#define NT   1024
#define SEAS 24
#define SLEN (NT + SEAS)   // 1048 seasonal output columns
#define CH   48            // main chunk length (multiple of SEAS)
#define SP   257           // LDS row stride in floats (odd -> bank-friendly)

__device__ __forceinline__ float frcp(float x) { return __builtin_amdgcn_rcpf(x); }

// Prefetch n4 float4s of y into register array Y (static indexing).
#define PREFETCH(Y, tb, n4)                                          \
    do {                                                             \
        _Pragma("unroll")                                            \
        for (int q = 0; q < 12; ++q)                                 \
            if (q < (n4)) (Y)[q] = *(const float4*)(yr + (tb) + 4*q);\
    } while (0)

// Process a chunk of length L starting at timestep tb (tb % 24 == 0).
// Y = register float4 array holding y[tb .. tb+L-1].
#define PROCESS(L, tb, Y)                                                         \
    do {                                                                          \
        float yy[(L)];                                                            \
        _Pragma("unroll")                                                         \
        for (int q = 0; q < (L)/4; ++q) {                                         \
            float4 v = (Y)[q];                                                    \
            yy[4*q]=v.x; yy[4*q+1]=v.y; yy[4*q+2]=v.z; yy[4*q+3]=v.w;             \
        }                                                                         \
        _Pragma("unroll")                                                         \
        for (int j = 0; j < (L); ++j) {                                           \
            const int sl = (j < SEAS) ? j : j - SEAS;                             \
            float s  = ring[sl];                                                  \
            float nl = fmaf(a, yy[j]*frcp(s),  ia*lev);                           \
            float nsv_ = fmaf(b, yy[j]*frcp(nl), ib*s);                           \
            ring[sl] = nsv_; lev = nl;                                            \
            lvS[j][tid] = nl;                                                     \
            nsS[j][tid] = nsv_;                                                   \
        }                                                                         \
        __syncthreads();                                                          \
        {                                                                         \
            const int NF = (L)/4;                                                 \
            _Pragma("unroll")                                                     \
            for (int kk = 0; kk < (L)/4; ++kk) {                                  \
                int f = tid + 256*kk;                                             \
                int r = f / NF, c = f % NF;                                       \
                float4 lvv = make_float4(lvS[4*c+0][r], lvS[4*c+1][r],            \
                                         lvS[4*c+2][r], lvS[4*c+3][r]);           \
                float4 nsv = make_float4(nsS[4*c+0][r], nsS[4*c+1][r],            \
                                         nsS[4*c+2][r], nsS[4*c+3][r]);           \
                *(float4*)(levels  + (size_t)(rbase + r) * NT   + (tb) + 4*c) = lvv; \
                *(float4*)(seasout + (size_t)(rbase + r) * SLEN + SEAS + (tb) + 4*c) = nsv; \
            }                                                                     \
        }                                                                         \
        __syncthreads();                                                          \
    } while (0)

__global__ __launch_bounds__(256, 1) void es_kernel(
    const float* __restrict__ y,
    const int*   __restrict__ idxs,
    const float* __restrict__ lev_sms,
    const float* __restrict__ seas_sms,
    const float* __restrict__ init_seas,
    float* __restrict__ levels,
    float* __restrict__ seasout)
{
    __shared__ float lvS[CH][SP];
    __shared__ float nsS[CH][SP];

    const int tid   = threadIdx.x;
    const int rbase = blockIdx.x * 256;
    const int i     = rbase + tid;
    const int id    = idxs[i];

    const float a  = 1.0f / (1.0f + __expf(-lev_sms[id]));
    const float b  = 1.0f / (1.0f + __expf(-seas_sms[id]));
    const float ia = 1.0f - a, ib = 1.0f - b;

    const float* yr = y + (size_t)i * NT;

    // season ring in registers (static indexing everywhere)
    float ring[SEAS];
    {
        const float* isrow = init_seas + (size_t)id * SEAS;
        #pragma unroll
        for (int k = 0; k < SEAS; ++k) ring[k] = __expf(isrow[k]);
    }

    // issue prefetch of first main chunk (tb=24) early; latency hides under head
    float4 yA[12], yB[12];
    PREFETCH(yA, SEAS, 12);

    float lev;  // running level, carried through head + main chunks

    // ---- head: t = 0..23 (direct per-thread stores; ~3% of traffic) ----
    {
        float* lr = levels  + (size_t)i * NT;
        float* sr = seasout + (size_t)i * SLEN;

        float yb[SEAS];
        #pragma unroll
        for (int k = 0; k < SEAS/4; ++k) {
            float4 v = ((const float4*)yr)[k];
            yb[4*k]=v.x; yb[4*k+1]=v.y; yb[4*k+2]=v.z; yb[4*k+3]=v.w;
        }

        lev = yb[0] * frcp(ring[0]);

        float lv[SEAS];
        float sh[2*SEAS];
        lv[0] = lev;
        #pragma unroll
        for (int k = 0; k < SEAS; ++k) sh[k] = ring[k];
        sh[SEAS] = ring[0];

        #pragma unroll
        for (int j = 1; j < SEAS; ++j) {
            float s = ring[j], yt = yb[j];
            float nl = fmaf(a, yt * frcp(s), ia * lev);
            float ns_ = fmaf(b, yt * frcp(nl), ib * s);
            ring[j] = ns_; lev = nl;
            lv[j] = nl; sh[SEAS + j] = ns_;
        }
        #pragma unroll
        for (int k = 0; k < SEAS/4; ++k)
            ((float4*)lr)[k] = make_float4(lv[4*k],lv[4*k+1],lv[4*k+2],lv[4*k+3]);
        #pragma unroll
        for (int k = 0; k < (2*SEAS)/4; ++k)
            ((float4*)sr)[k] = make_float4(sh[4*k],sh[4*k+1],sh[4*k+2],sh[4*k+3]);
    }

    // ---- main chunks: tb = 24 + 48k, k = 0..19 (t = 24..983) ----
    for (int k = 0; k < 20; k += 2) {
        PREFETCH(yB, SEAS + 48*(k+1), 12);
        PROCESS(CH, SEAS + 48*k, yA);
        if (k == 18) { PREFETCH(yA, 984, 10); }
        else         { PREFETCH(yA, SEAS + 48*(k+2), 12); }
        PROCESS(CH, SEAS + 48*(k+1), yB);
    }

    // ---- tail: t = 984..1023 (40 steps, 984 % 24 == 0) ----
    PROCESS(40, 984, yA);
}

extern "C" void kernel_launch(void* const* d_in, const int* in_sizes, int n_in,
                              void* d_out, int out_size, void* d_ws, size_t ws_size,
                              hipStream_t stream) {
    const float* y         = (const float*)d_in[0];
    const int*   idxs      = (const int*)d_in[1];
    const float* lev_sms   = (const float*)d_in[2];
    const float* seas_sms  = (const float*)d_in[3];
    const float* init_seas = (const float*)d_in[4];

    float* levels  = (float*)d_out;
    float* seasout = levels + (size_t)NSER * NT;

    es_kernel<<<NSER/256, 256, 0, stream>>>(y, idxs, lev_sms, seas_sms, init_seas,
                                            levels, seasout);
}

// Round 3
// 350.984 us; speedup vs baseline: 1.3596x; 1.0073x over previous
//
#include <hip/hip_runtime.h>

#define NSER 65536
#define NT   1024
#define SEAS 24
#define SLEN (NT + SEAS)   // 1048 seasonal output columns
#define CH   48            // main chunk length (multiple of SEAS)
#define SP   65            // LDS row stride in floats (odd -> <=2-3 way banks)

__device__ __forceinline__ float frcp(float x) { return __builtin_amdgcn_rcpf(x); }

// Prefetch n4 float4s of y into register array Y (static indexing).
#define PREFETCH(Y, tb, n4)                                          \
    do {                                                             \
        _Pragma("unroll")                                            \
        for (int q = 0; q < 12; ++q)                                 \
            if (q < (n4)) (Y)[q] = *(const float4*)(yr + (tb) + 4*q);\
    } while (0)

// Process a chunk of length L starting at timestep tb (tb % 24 == 0).
// Wave-private LDS staging: NO barriers anywhere (cross-lane within a wave
// through LDS is ordered by lgkmcnt, which the compiler inserts).
#define PROCESS(L, tb, Y)                                                         \
    do {                                                                          \
        float yy[(L)];                                                            \
        _Pragma("unroll")                                                         \
        for (int q = 0; q < (L)/4; ++q) {                                         \
            float4 v = (Y)[q];                                                    \
            yy[4*q]=v.x; yy[4*q+1]=v.y; yy[4*q+2]=v.z; yy[4*q+3]=v.w;             \
        }                                                                         \
        _Pragma("unroll")                                                         \
        for (int j = 0; j < (L); ++j) {                                           \
            const int sl = (j < SEAS) ? j : j - SEAS;                             \
            float s   = ring[sl];                                                 \
            float c_  = (a * yy[j]) * frcp(s);                                    \
            float nl  = fmaf(ia, lev, c_);        /* 1-fma dependence chain */    \
            float ns_ = fmaf(ib, s, (b * yy[j]) * frcp(nl));                      \
            ring[sl] = ns_; lev = nl;                                             \
            lvW[j][lane] = nl;                                                    \
            nsW[j][lane] = ns_;                                                   \
        }                                                                         \
        {                                                                         \
            const int NF = (L)/4;                                                 \
            _Pragma("unroll")                                                     \
            for (int kk = 0; kk < (L)/4; ++kk) {                                  \
                int f = lane + 64*kk;                                             \
                int r = f / NF, c = f % NF;                                       \
                float4 lvv = make_float4(lvW[4*c+0][r], lvW[4*c+1][r],            \
                                         lvW[4*c+2][r], lvW[4*c+3][r]);           \
                float4 nsv = make_float4(nsW[4*c+0][r], nsW[4*c+1][r],            \
                                         nsW[4*c+2][r], nsW[4*c+3][r]);           \
                *(float4*)(levels  + (size_t)(wbase + r) * NT   + (tb) + 4*c) = lvv; \
                *(float4*)(seasout + (size_t)(wbase + r) * SLEN + SEAS + (tb) + 4*c) = nsv; \
            }                                                                     \
        }                                                                         \
    } while (0)

__global__ __launch_bounds__(256, 1) void es_kernel(
    const float* __restrict__ y,
    const int*   __restrict__ idxs,
    const float* __restrict__ lev_sms,
    const float* __restrict__ seas_sms,
    const float* __restrict__ init_seas,
    float* __restrict__ levels,
    float* __restrict__ seasout)
{
    __shared__ float lvS[4][CH][SP];   // per-wave private regions
    __shared__ float nsS[4][CH][SP];

    const int tid   = threadIdx.x;
    const int w     = tid >> 6;
    const int lane  = tid & 63;
    const int rbase = blockIdx.x * 256;
    const int wbase = rbase + (w << 6);
    const int i     = wbase + lane;

    float (*lvW)[SP] = lvS[w];
    float (*nsW)[SP] = nsS[w];

    const int id = idxs[i];
    const float a  = 1.0f / (1.0f + __expf(-lev_sms[id]));
    const float b  = 1.0f / (1.0f + __expf(-seas_sms[id]));
    const float ia = 1.0f - a, ib = 1.0f - b;

    const float* yr = y + (size_t)i * NT;

    // season ring in registers (static indexing everywhere)
    float ring[SEAS];
    {
        const float4* isr = (const float4*)(init_seas + (size_t)id * SEAS);
        #pragma unroll
        for (int q = 0; q < SEAS/4; ++q) {
            float4 v = isr[q];
            ring[4*q+0] = __expf(v.x); ring[4*q+1] = __expf(v.y);
            ring[4*q+2] = __expf(v.z); ring[4*q+3] = __expf(v.w);
        }
    }

    // deep prefetch: first main chunk issued before head compute
    float4 yA[12], yB[12];
    PREFETCH(yA, SEAS, 12);

    float lev;

    // ---- head: t = 0..23 (also staged through LDS -> coalesced stores) ----
    {
        float yb[SEAS];
        #pragma unroll
        for (int k = 0; k < SEAS/4; ++k) {
            float4 v = ((const float4*)yr)[k];
            yb[4*k]=v.x; yb[4*k+1]=v.y; yb[4*k+2]=v.z; yb[4*k+3]=v.w;
        }

        lev = yb[0] * frcp(ring[0]);

        float lv[SEAS];
        float sh[2*SEAS];
        lv[0] = lev;
        #pragma unroll
        for (int k = 0; k < SEAS; ++k) sh[k] = ring[k];
        sh[SEAS] = ring[0];

        #pragma unroll
        for (int j = 1; j < SEAS; ++j) {
            float s   = ring[j];
            float c_  = (a * yb[j]) * frcp(s);
            float nl  = fmaf(ia, lev, c_);
            float ns_ = fmaf(ib, s, (b * yb[j]) * frcp(nl));
            ring[j] = ns_; lev = nl;
            lv[j] = nl; sh[SEAS + j] = ns_;
        }

        // stage levels[0..23] and seasout[0..47] in LDS, flush coalesced
        #pragma unroll
        for (int j = 0; j < SEAS; ++j) lvW[j][lane] = lv[j];
        #pragma unroll
        for (int j = 0; j < 2*SEAS; ++j) nsW[j][lane] = sh[j];

        #pragma unroll
        for (int kk = 0; kk < 6; ++kk) {            // levels: 64 rows x 6 float4
            int f = lane + 64*kk;
            int r = f / 6, c = f % 6;
            float4 lvv = make_float4(lvW[4*c+0][r], lvW[4*c+1][r],
                                     lvW[4*c+2][r], lvW[4*c+3][r]);
            *(float4*)(levels + (size_t)(wbase + r) * NT + 4*c) = lvv;
        }
        #pragma unroll
        for (int kk = 0; kk < 12; ++kk) {           // seasout: 64 rows x 12 float4
            int f = lane + 64*kk;
            int r = f / 12, c = f % 12;
            float4 nsv = make_float4(nsW[4*c+0][r], nsW[4*c+1][r],
                                     nsW[4*c+2][r], nsW[4*c+3][r]);
            *(float4*)(seasout + (size_t)(wbase + r) * SLEN + 4*c) = nsv;
        }
    }

    // ---- main chunks: tb = 24 + 48k, k = 0..19 (t = 24..983) ----
    for (int k = 0; k < 20; k += 2) {
        PREFETCH(yB, SEAS + 48*(k+1), 12);
        PROCESS(CH, SEAS + 48*k, yA);
        if (k == 18) { PREFETCH(yA, 984, 10); }
        else         { PREFETCH(yA, SEAS + 48*(k+2), 12); }
        PROCESS(CH, SEAS + 48*(k+1), yB);
    }

    // ---- tail: t = 984..1023 (40 steps, 984 % 24 == 0) ----
    PROCESS(40, 984, yA);
}

extern "C" void kernel_launch(void* const* d_in, const int* in_sizes, int n_in,
                              void* d_out, int out_size, void* d_ws, size_t ws_size,
                              hipStream_t stream) {
    const float* y         = (const float*)d_in[0];
    const int*   idxs      = (const int*)d_in[1];
    const float* lev_sms   = (const float*)d_in[2];
    const float* seas_sms  = (const float*)d_in[3];
    const float* init_seas = (const float*)d_in[4];

    float* levels  = (float*)d_out;
    float* seasout = levels + (size_t)NSER * NT;

    es_kernel<<<NSER/256, 256, 0, stream>>>(y, idxs, lev_sms, seas_sms, init_seas,
                                            levels, seasout);
}

// Round 4
// 260.504 us; speedup vs baseline: 1.8318x; 1.3473x over previous
//
#include <hip/hip_runtime.h>

#define NSER 65536
#define NT   1024
#define SEAS 24
#define SLEN (NT + SEAS)   // 1048 seasonal output columns
#define NW   43            // windows w=0..42; last covers t=1008..1023 (16 steps)

__device__ __forceinline__ float frcp(float x) { return __builtin_amdgcn_rcpf(x); }

// One 32-lane group per series. Lane j handles timestep t = 24*w + j (j < 24).
// Level recurrence is linear: lev_t = ia*lev_{t-1} + a*y_t/s_t, and with
// window == SEASONALITY the seasonal feedback s_t = ns_{t-24} is LANE-LOCAL.
// Window 0 folds the reference's special t=0 step via per-lane overrides
// (lane 0: a_eff=1 -> lev0 = y0/s0; b_eff=0 -> "ns_0" = s0[0], which both
// fills seasonalities col 24 and feeds s_24 = s0[0] for window 1).
__global__ __launch_bounds__(256) void es_scan_kernel(
    const float* __restrict__ y,
    const int*   __restrict__ idxs,
    const float* __restrict__ lev_sms,
    const float* __restrict__ seas_sms,
    const float* __restrict__ init_seas,
    float* __restrict__ levels,
    float* __restrict__ seasout)
{
    const int tid = threadIdx.x;
    const int grp = tid >> 5;                 // 8 series per 256-thread block
    const int j   = tid & 31;                 // lane within group; j<24 active
    const int i   = blockIdx.x * 8 + grp;     // series index
    const bool act = (j < SEAS);

    const int id = idxs[i];
    const float a  = 1.0f / (1.0f + __expf(-lev_sms[id]));
    const float b  = 1.0f / (1.0f + __expf(-seas_sms[id]));
    const float ia = 1.0f - a, ib = 1.0f - b;

    // scan-round weights ia^{1,2,4,8,16} and per-lane carry weight ia^(j+1)
    const float ia1 = ia, ia2 = ia1*ia1, ia4 = ia2*ia2, ia8 = ia4*ia4, ia16 = ia8*ia8;
    const float iapow = __powf(ia, (float)(j + 1));

    const size_t lrow = (size_t)i * NT;
    const size_t srow = (size_t)i * SLEN;
    const float* yrow = y + lrow;

    // initial seasonal state s = exp(init_seas[id][j]); also emit cols 0..23
    float s = 1.0f;
    if (act) {
        s = __expf(init_seas[(size_t)id * SEAS + j]);
        seasout[srow + j] = s;
    }

    float lev_prev = 0.0f;

    for (int w = 0; w < NW; ++w) {
        const int t = SEAS * w + j;
        const bool on = act && (t < NT);

        float yt = 1.0f;
        if (on) yt = yrow[t];

        // window-0 lane-0 overrides (the reference's t=0 special step)
        float ae = a, be = b, ibe = ib;
        if (w == 0 && j == 0) { ae = 1.0f; be = 0.0f; ibe = 1.0f; }

        // c_j = a*y/s, then weighted inclusive scan over lanes 0..23:
        // x_j = sum_{m<=j} ia^{j-m} c_m   (Kogge-Stone, 5 rounds)
        float x = ae * yt * frcp(s);
        float tsh;
        tsh = __shfl_up(x, 1, 32);  if (j >= 1)  x = fmaf(ia1,  tsh, x);
        tsh = __shfl_up(x, 2, 32);  if (j >= 2)  x = fmaf(ia2,  tsh, x);
        tsh = __shfl_up(x, 4, 32);  if (j >= 4)  x = fmaf(ia4,  tsh, x);
        tsh = __shfl_up(x, 8, 32);  if (j >= 8)  x = fmaf(ia8,  tsh, x);
        tsh = __shfl_up(x, 16, 32); if (j >= 16) x = fmaf(ia16, tsh, x);

        const float lev = fmaf(iapow, lev_prev, x);          // + ia^(j+1)*carry
        const float ns  = fmaf(ibe, s, be * yt * frcp(lev)); // seasonal update

        if (on) {
            levels[lrow + t]         = lev;  // coalesced: 24 consecutive floats
            seasout[srow + SEAS + t] = ns;   // coalesced: 24 consecutive floats
        }

        lev_prev = __shfl(lev, 23, 32);      // carry = last step of window
        s = ns;                              // lane-local seasonal feedback
    }
}

extern "C" void kernel_launch(void* const* d_in, const int* in_sizes, int n_in,
                              void* d_out, int out_size, void* d_ws, size_t ws_size,
                              hipStream_t stream) {
    const float* y         = (const float*)d_in[0];
    const int*   idxs      = (const int*)d_in[1];
    const float* lev_sms   = (const float*)d_in[2];
    const float* seas_sms  = (const float*)d_in[3];
    const float* init_seas = (const float*)d_in[4];

    float* levels  = (float*)d_out;
    float* seasout = levels + (size_t)NSER * NT;

    es_scan_kernel<<<NSER/8, 256, 0, stream>>>(y, idxs, lev_sms, seas_sms, init_seas,
                                               levels, seasout);
}